// Round 11
// baseline (113.628 us; speedup 1.0000x reference)
//
#include <hip/hip_runtime.h>
#include <hip/hip_bf16.h>

// SDPA, causal, b=16 t=2048 d=64. Outputs FP32: d_out = [ out | sm_qk ].
// R11 = R10 + zero-fill interleaved into phase 1 (store-pipe never idle).
// R10: LDS double-buffering (one barrier/iter), depth-2 reg prefetch,
// s_setprio around MFMA. Phase 1: lean rowsum (uncompensated). Phase 2:
// compensated QK^T (qh*kh+qh*kl+ql*kh), P=exp*il fp32, PV via V^T LDS.
// Zero tiles z in [nkt,32) are written during phase-1 iters (z = nkt+kt,
// stride nkt -> each tile exactly once), so global stores flow from t=0.
// XCD batch clustering + causal pairing as R5.

#define BATCHES 16
#define SEQ 2048
#define DIM 64
#define QB 64
#define KT 64
#define NQB (SEQ / QB) /* 32 */
#define KLD 72   /* K LDS row stride, shorts */
#define VLD 72   /* V^T LDS row stride, shorts */
#define PFLD 68  /* fp32 P-tile stride, floats */

typedef __attribute__((ext_vector_type(8))) short bf16x8;
typedef __attribute__((ext_vector_type(4))) short short4v;
typedef __attribute__((ext_vector_type(4))) float f32x4;

static __device__ __forceinline__ short f2bf(float f) {
    return __builtin_bit_cast(short, __float2bfloat16(f));
}
static __device__ __forceinline__ float bf2f(short s) {
    unsigned int u = ((unsigned int)(unsigned short)s) << 16;
    return __builtin_bit_cast(float, u);
}
static __device__ __forceinline__ void split8(f32x4 a, f32x4 b, float sc,
                                              bf16x8& h, bf16x8& l) {
#pragma unroll
    for (int e = 0; e < 4; ++e) {
        float x = a[e] * sc;
        short hb = f2bf(x);
        h[e] = hb; l[e] = f2bf(x - bf2f(hb));
    }
#pragma unroll
    for (int e = 0; e < 4; ++e) {
        float x = b[e] * sc;
        short hb = f2bf(x);
        h[4 + e] = hb; l[4 + e] = f2bf(x - bf2f(hb));
    }
}

__global__ __launch_bounds__(256, 2) void sdpa_fused(
    const float* __restrict__ Qg, const float* __restrict__ Kg,
    const float* __restrict__ Vg, float* __restrict__ Og, float* __restrict__ Pg)
{
    const int i = blockIdx.x;
    const int g = i & 7;
    const int j = i >> 3;             // 0..63
    const int b = 2 * g + (j >> 5);
    const int jj = j & 31;
    const int qb = (j < 32) ? jj : (31 - jj);
    const int q0 = qb * QB;

    const int tid = threadIdx.x;
    const int lane = tid & 63;
    const int wave = tid >> 6;
    const int lo = lane & 15;
    const int hi = lane >> 4;
    const int sr = tid >> 4;          // K stage rows: sr+16*ii
    const int sc = (tid & 15) * 4;    // stage col
    const int vr = (tid >> 4) * 4;    // V stage rows: vr..vr+3

    __shared__ short Khi[2][KT * KLD];
    __shared__ short Klo[2][KT * KLD];
    __shared__ short Vt [2][DIM * VLD];
    __shared__ float Pf[QB * PFLD];   // wave-private bands, no cross-wave sync

    const float* qB = Qg + (size_t)b * SEQ * DIM;
    const float* kB = Kg + (size_t)b * SEQ * DIM;
    const float* vB = Vg + (size_t)b * SEQ * DIM;

    bf16x8 qa0h, qa0l, qa1h, qa1l;
    {
        const float* qr = &qB[(size_t)(q0 + wave * 16 + lo) * DIM + hi * 8];
        split8(*(const f32x4*)qr,        *(const f32x4*)(qr + 4),  0.125f, qa0h, qa0l);
        split8(*(const f32x4*)(qr + 32), *(const f32x4*)(qr + 36), 0.125f, qa1h, qa1l);
    }

    const int nkt = qb + 1;
    float rl[4] = {0.f, 0.f, 0.f, 0.f};

    // zero-fill coords (one 64x64 fp32 tile = 256 thr x 64 B)
    const int zr = tid >> 2;
    const int zc = (tid & 3) * 16;
    float* zrow = &Pg[((size_t)(b * SEQ) + q0 + zr) * SEQ + zc];

    auto loadK = [&](f32x4* kp, int kt) {
#pragma unroll
        for (int ii = 0; ii < 4; ++ii)
            kp[ii] = *(const f32x4*)&kB[(size_t)(kt * KT + sr + 16 * ii) * DIM + sc];
    };
    auto loadV = [&](f32x4* vp, int kt) {
#pragma unroll
        for (int ii = 0; ii < 4; ++ii)
            vp[ii] = *(const f32x4*)&vB[(size_t)(kt * KT + vr + ii) * DIM + sc];
    };
    auto stageKhi = [&](int buf, const f32x4* kp) {
#pragma unroll
        for (int ii = 0; ii < 4; ++ii) {
            short4v hh;
#pragma unroll
            for (int e = 0; e < 4; ++e) hh[e] = f2bf(kp[ii][e]);
            *(short4v*)&Khi[buf][(sr + 16 * ii) * KLD + sc] = hh;
        }
    };
    auto stageKsplit = [&](int buf, const f32x4* kp) {
#pragma unroll
        for (int ii = 0; ii < 4; ++ii) {
            short4v hh, ll;
#pragma unroll
            for (int e = 0; e < 4; ++e) {
                short hb = f2bf(kp[ii][e]);
                hh[e] = hb; ll[e] = f2bf(kp[ii][e] - bf2f(hb));
            }
            *(short4v*)&Khi[buf][(sr + 16 * ii) * KLD + sc] = hh;
            *(short4v*)&Klo[buf][(sr + 16 * ii) * KLD + sc] = ll;
        }
    };
    auto stageVt = [&](int buf, const f32x4* vp) {
#pragma unroll
        for (int e = 0; e < 4; ++e) {
            short4v tv;
#pragma unroll
            for (int ii = 0; ii < 4; ++ii) tv[ii] = f2bf(vp[ii][e]);
            *(short4v*)&Vt[buf][(sc + e) * VLD + vr] = tv;
        }
    };

    // ============ phase 1: l = sum exp(S), lean; zero-fill interleaved ======
    {
        f32x4 kp[4];
        loadK(kp, 0);
        stageKhi(0, kp);
        if (nkt > 1) loadK(kp, 1);
        __syncthreads();
        for (int kt = 0; kt < nkt; ++kt) {
            const int cur = kt & 1;
            if (kt + 1 < nkt) {
                stageKhi(cur ^ 1, kp);          // overlaps with compute below
                if (kt + 2 < nkt) loadK(kp, kt + 2);
            }
            // zero-fill masked tiles, strided so each is written exactly once
            for (int z = nkt + kt; z < NQB; z += nkt) {
                const f32x4 zv = {0.f, 0.f, 0.f, 0.f};
                float* d = zrow + z * KT;
#pragma unroll
                for (int iw = 0; iw < 4; ++iw)
                    *(f32x4*)&d[4 * iw] = zv;
            }
            const int nmax = (kt == qb) ? (wave + 1) : 4;
            for (int n = 0; n < nmax; ++n) {
                bf16x8 kh0 = *(const bf16x8*)&Khi[cur][(16 * n + lo) * KLD + hi * 8];
                bf16x8 kh1 = *(const bf16x8*)&Khi[cur][(16 * n + lo) * KLD + 32 + hi * 8];
                f32x4 acc = {0.f, 0.f, 0.f, 0.f};
                __builtin_amdgcn_s_setprio(1);
                acc = __builtin_amdgcn_mfma_f32_16x16x32_bf16(qa0h, kh0, acc, 0, 0, 0);
                acc = __builtin_amdgcn_mfma_f32_16x16x32_bf16(qa1h, kh1, acc, 0, 0, 0);
                __builtin_amdgcn_s_setprio(0);
                if (kt < qb) {
#pragma unroll
                    for (int jx = 0; jx < 4; ++jx) rl[jx] += __expf(acc[jx]);
                } else {
                    const int col = 16 * n + lo;
#pragma unroll
                    for (int jx = 0; jx < 4; ++jx)
                        if (col <= wave * 16 + hi * 4 + jx) rl[jx] += __expf(acc[jx]);
                }
            }
            __syncthreads();
        }
    }
#pragma unroll
    for (int m = 1; m <= 8; m <<= 1)
#pragma unroll
        for (int jx = 0; jx < 4; ++jx) rl[jx] += __shfl_xor(rl[jx], m, 16);
    float il[4];
#pragma unroll
    for (int jx = 0; jx < 4; ++jx) il[jx] = 1.0f / rl[jx];

    // ============ phase 2: P = exp(S)*il (fp32) + O = P*V ============
    f32x4 o[4];
#pragma unroll
    for (int n = 0; n < 4; ++n) { o[n][0] = 0.f; o[n][1] = 0.f; o[n][2] = 0.f; o[n][3] = 0.f; }

    {
        f32x4 kp[4], vp[4];
        loadK(kp, 0); loadV(vp, 0);
        stageKsplit(0, kp); stageVt(0, vp);
        if (nkt > 1) { loadK(kp, 1); loadV(vp, 1); }
        __syncthreads();

        for (int kt = 0; kt < nkt; ++kt) {
            const int cur = kt & 1;
            if (kt + 1 < nkt) {
                stageKsplit(cur ^ 1, kp);
                stageVt(cur ^ 1, vp);
                if (kt + 2 < nkt) { loadK(kp, kt + 2); loadV(vp, kt + 2); }
            }
            // S = QK^T (compensated) -> Pf (wave-private band)
#pragma unroll
            for (int n = 0; n < 4; ++n) {
                const bool fm = (kt == qb) && (n > wave);  // wave-uniform
                f32x4 acc = {0.f, 0.f, 0.f, 0.f};
                if (!fm) {
                    bf16x8 kh0 = *(const bf16x8*)&Khi[cur][(16 * n + lo) * KLD + hi * 8];
                    bf16x8 kh1 = *(const bf16x8*)&Khi[cur][(16 * n + lo) * KLD + 32 + hi * 8];
                    bf16x8 kl0 = *(const bf16x8*)&Klo[cur][(16 * n + lo) * KLD + hi * 8];
                    bf16x8 kl1 = *(const bf16x8*)&Klo[cur][(16 * n + lo) * KLD + 32 + hi * 8];
                    __builtin_amdgcn_s_setprio(1);
                    acc = __builtin_amdgcn_mfma_f32_16x16x32_bf16(qa0h, kh0, acc, 0, 0, 0);
                    acc = __builtin_amdgcn_mfma_f32_16x16x32_bf16(qa1h, kh1, acc, 0, 0, 0);
                    acc = __builtin_amdgcn_mfma_f32_16x16x32_bf16(qa0h, kl0, acc, 0, 0, 0);
                    acc = __builtin_amdgcn_mfma_f32_16x16x32_bf16(qa1h, kl1, acc, 0, 0, 0);
                    acc = __builtin_amdgcn_mfma_f32_16x16x32_bf16(qa0l, kh0, acc, 0, 0, 0);
                    acc = __builtin_amdgcn_mfma_f32_16x16x32_bf16(qa1l, kh1, acc, 0, 0, 0);
                    __builtin_amdgcn_s_setprio(0);
                }
                const int col = 16 * n + lo;
#pragma unroll
                for (int jx = 0; jx < 4; ++jx) {
                    const int row = wave * 16 + hi * 4 + jx;
                    const float p = (!fm && (kt < qb || col <= row)) ? __expf(acc[jx]) * il[jx] : 0.f;
                    Pf[row * PFLD + col] = p;
                }
            }
            // stream own P band to global
            {
                const int r = wave * 16 + (lane >> 2);
                const int c4 = (lane & 3) * 4;
                float* dst = &Pg[((size_t)(b * SEQ) + q0 + r) * SEQ + kt * KT + c4];
                const float* src = &Pf[r * PFLD + c4];
#pragma unroll
                for (int iw = 0; iw < 4; ++iw)
                    *(f32x4*)&dst[16 * iw] = *(const f32x4*)&src[16 * iw];
            }
            // PV: A-frag from own Pf band, B-frag from Vt[cur]
            {
                const float* pr = &Pf[(wave * 16 + lo) * PFLD + hi * 8];
                bf16x8 pa0, pa1;
                {
                    f32x4 a = *(const f32x4*)pr, c2 = *(const f32x4*)(pr + 4);
                    f32x4 d = *(const f32x4*)(pr + 32), e2 = *(const f32x4*)(pr + 36);
#pragma unroll
                    for (int e = 0; e < 4; ++e) {
                        pa0[e] = f2bf(a[e]); pa0[4 + e] = f2bf(c2[e]);
                        pa1[e] = f2bf(d[e]); pa1[4 + e] = f2bf(e2[e]);
                    }
                }
                __builtin_amdgcn_s_setprio(1);
#pragma unroll
                for (int n = 0; n < 4; ++n) {
                    bf16x8 vb0 = *(const bf16x8*)&Vt[cur][(16 * n + lo) * VLD + hi * 8];
                    bf16x8 vb1 = *(const bf16x8*)&Vt[cur][(16 * n + lo) * VLD + 32 + hi * 8];
                    o[n] = __builtin_amdgcn_mfma_f32_16x16x32_bf16(pa0, vb0, o[n], 0, 0, 0);
                    o[n] = __builtin_amdgcn_mfma_f32_16x16x32_bf16(pa1, vb1, o[n], 0, 0, 0);
                }
                __builtin_amdgcn_s_setprio(0);
            }
            __syncthreads();
        }
    }

    // ---- O (already normalized: PV used exp*il), fp32 ----
    {
        float* og = &Og[((size_t)(b * SEQ) + q0 + wave * 16 + hi * 4) * DIM + lo];
#pragma unroll
        for (int jx = 0; jx < 4; ++jx)
#pragma unroll
            for (int n = 0; n < 4; ++n)
                og[jx * DIM + n * 16] = o[n][jx];
    }
}

extern "C" void kernel_launch(void* const* d_in, const int* in_sizes, int n_in,
                              void* d_out, int out_size, void* d_ws, size_t ws_size,
                              hipStream_t stream) {
    const float* q = (const float*)d_in[0];
    const float* k = (const float*)d_in[1];
    const float* v = (const float*)d_in[2];
    float* out  = (float*)d_out;                        // [B,T,D] fp32
    float* smqk = out + (size_t)BATCHES * SEQ * DIM;    // [B,T,T] fp32

    sdpa_fused<<<NQB * BATCHES, 256, 0, stream>>>(q, k, v, out, smqk);
}

// Round 12
// 105.477 us; speedup vs baseline: 1.0773x; 1.0773x over previous
//
#include <hip/hip_runtime.h>
#include <hip/hip_bf16.h>

// SDPA, causal, b=16 t=2048 d=64. Outputs FP32: d_out = [ out | sm_qk ].
// R12 = R10 + T4 counted-wait barriers: in-loop __syncthreads() replaced by
// {s_waitcnt lgkmcnt(0); s_barrier} so global loads/stores stay in flight
// across barriers (compiler's vmcnt(0)-before-s_barrier drain removed).
// R10 base: LDS double-buffer (one barrier/iter), depth-2 reg prefetch,
// s_setprio around MFMA clusters. Phase 1: lean rowsum (uncompensated).
// Phase 2: compensated QK^T (qh*kh+qh*kl+ql*kh), P=exp*il fp32, PV via V^T.
// Tail zero-fill (R11's interleave reverted - it regressed).
// XCD batch clustering + causal pairing as R5.

#define BATCHES 16
#define SEQ 2048
#define DIM 64
#define QB 64
#define KT 64
#define NQB (SEQ / QB) /* 32 */
#define KLD 72   /* K LDS row stride, shorts */
#define VLD 72   /* V^T LDS row stride, shorts */
#define PFLD 68  /* fp32 P-tile stride, floats */

// LDS-visibility barrier WITHOUT the compiler's vmcnt(0) drain:
#define BAR() do { asm volatile("s_waitcnt lgkmcnt(0)" ::: "memory"); \
                   __builtin_amdgcn_s_barrier(); } while (0)

typedef __attribute__((ext_vector_type(8))) short bf16x8;
typedef __attribute__((ext_vector_type(4))) short short4v;
typedef __attribute__((ext_vector_type(4))) float f32x4;

static __device__ __forceinline__ short f2bf(float f) {
    return __builtin_bit_cast(short, __float2bfloat16(f));
}
static __device__ __forceinline__ float bf2f(short s) {
    unsigned int u = ((unsigned int)(unsigned short)s) << 16;
    return __builtin_bit_cast(float, u);
}
static __device__ __forceinline__ void split8(f32x4 a, f32x4 b, float sc,
                                              bf16x8& h, bf16x8& l) {
#pragma unroll
    for (int e = 0; e < 4; ++e) {
        float x = a[e] * sc;
        short hb = f2bf(x);
        h[e] = hb; l[e] = f2bf(x - bf2f(hb));
    }
#pragma unroll
    for (int e = 0; e < 4; ++e) {
        float x = b[e] * sc;
        short hb = f2bf(x);
        h[4 + e] = hb; l[4 + e] = f2bf(x - bf2f(hb));
    }
}

__global__ __launch_bounds__(256, 2) void sdpa_fused(
    const float* __restrict__ Qg, const float* __restrict__ Kg,
    const float* __restrict__ Vg, float* __restrict__ Og, float* __restrict__ Pg)
{
    const int i = blockIdx.x;
    const int g = i & 7;
    const int j = i >> 3;             // 0..63
    const int b = 2 * g + (j >> 5);
    const int jj = j & 31;
    const int qb = (j < 32) ? jj : (31 - jj);
    const int q0 = qb * QB;

    const int tid = threadIdx.x;
    const int lane = tid & 63;
    const int wave = tid >> 6;
    const int lo = lane & 15;
    const int hi = lane >> 4;
    const int sr = tid >> 4;          // K stage rows: sr+16*ii
    const int sc = (tid & 15) * 4;    // stage col
    const int vr = (tid >> 4) * 4;    // V stage rows: vr..vr+3

    __shared__ short Khi[2][KT * KLD];
    __shared__ short Klo[2][KT * KLD];
    __shared__ short Vt [2][DIM * VLD];
    __shared__ float Pf[QB * PFLD];   // wave-private bands, no cross-wave sync

    const float* qB = Qg + (size_t)b * SEQ * DIM;
    const float* kB = Kg + (size_t)b * SEQ * DIM;
    const float* vB = Vg + (size_t)b * SEQ * DIM;

    bf16x8 qa0h, qa0l, qa1h, qa1l;
    {
        const float* qr = &qB[(size_t)(q0 + wave * 16 + lo) * DIM + hi * 8];
        split8(*(const f32x4*)qr,        *(const f32x4*)(qr + 4),  0.125f, qa0h, qa0l);
        split8(*(const f32x4*)(qr + 32), *(const f32x4*)(qr + 36), 0.125f, qa1h, qa1l);
    }

    const int nkt = qb + 1;
    float rl[4] = {0.f, 0.f, 0.f, 0.f};

    auto loadK = [&](f32x4* kp, int kt) {
#pragma unroll
        for (int ii = 0; ii < 4; ++ii)
            kp[ii] = *(const f32x4*)&kB[(size_t)(kt * KT + sr + 16 * ii) * DIM + sc];
    };
    auto loadV = [&](f32x4* vp, int kt) {
#pragma unroll
        for (int ii = 0; ii < 4; ++ii)
            vp[ii] = *(const f32x4*)&vB[(size_t)(kt * KT + vr + ii) * DIM + sc];
    };
    auto stageKhi = [&](int buf, const f32x4* kp) {
#pragma unroll
        for (int ii = 0; ii < 4; ++ii) {
            short4v hh;
#pragma unroll
            for (int e = 0; e < 4; ++e) hh[e] = f2bf(kp[ii][e]);
            *(short4v*)&Khi[buf][(sr + 16 * ii) * KLD + sc] = hh;
        }
    };
    auto stageKsplit = [&](int buf, const f32x4* kp) {
#pragma unroll
        for (int ii = 0; ii < 4; ++ii) {
            short4v hh, ll;
#pragma unroll
            for (int e = 0; e < 4; ++e) {
                short hb = f2bf(kp[ii][e]);
                hh[e] = hb; ll[e] = f2bf(kp[ii][e] - bf2f(hb));
            }
            *(short4v*)&Khi[buf][(sr + 16 * ii) * KLD + sc] = hh;
            *(short4v*)&Klo[buf][(sr + 16 * ii) * KLD + sc] = ll;
        }
    };
    auto stageVt = [&](int buf, const f32x4* vp) {
#pragma unroll
        for (int e = 0; e < 4; ++e) {
            short4v tv;
#pragma unroll
            for (int ii = 0; ii < 4; ++ii) tv[ii] = f2bf(vp[ii][e]);
            *(short4v*)&Vt[buf][(sc + e) * VLD + vr] = tv;
        }
    };

    // ================ phase 1: l = sum exp(S), lean ================
    {
        f32x4 kp[4];
        loadK(kp, 0);
        stageKhi(0, kp);
        if (nkt > 1) loadK(kp, 1);
        BAR();
        for (int kt = 0; kt < nkt; ++kt) {
            const int cur = kt & 1;
            if (kt + 1 < nkt) {
                stageKhi(cur ^ 1, kp);          // overlaps with compute below
                if (kt + 2 < nkt) loadK(kp, kt + 2);
            }
            const int nmax = (kt == qb) ? (wave + 1) : 4;
            for (int n = 0; n < nmax; ++n) {
                bf16x8 kh0 = *(const bf16x8*)&Khi[cur][(16 * n + lo) * KLD + hi * 8];
                bf16x8 kh1 = *(const bf16x8*)&Khi[cur][(16 * n + lo) * KLD + 32 + hi * 8];
                f32x4 acc = {0.f, 0.f, 0.f, 0.f};
                __builtin_amdgcn_s_setprio(1);
                acc = __builtin_amdgcn_mfma_f32_16x16x32_bf16(qa0h, kh0, acc, 0, 0, 0);
                acc = __builtin_amdgcn_mfma_f32_16x16x32_bf16(qa1h, kh1, acc, 0, 0, 0);
                __builtin_amdgcn_s_setprio(0);
                if (kt < qb) {
#pragma unroll
                    for (int jx = 0; jx < 4; ++jx) rl[jx] += __expf(acc[jx]);
                } else {
                    const int col = 16 * n + lo;
#pragma unroll
                    for (int jx = 0; jx < 4; ++jx)
                        if (col <= wave * 16 + hi * 4 + jx) rl[jx] += __expf(acc[jx]);
                }
            }
            BAR();
        }
    }
#pragma unroll
    for (int m = 1; m <= 8; m <<= 1)
#pragma unroll
        for (int jx = 0; jx < 4; ++jx) rl[jx] += __shfl_xor(rl[jx], m, 16);
    float il[4];
#pragma unroll
    for (int jx = 0; jx < 4; ++jx) il[jx] = 1.0f / rl[jx];

    // ============ phase 2: P = exp(S)*il (fp32) + O = P*V ============
    f32x4 o[4];
#pragma unroll
    for (int n = 0; n < 4; ++n) { o[n][0] = 0.f; o[n][1] = 0.f; o[n][2] = 0.f; o[n][3] = 0.f; }

    {
        f32x4 kp[4], vp[4];
        loadK(kp, 0); loadV(vp, 0);
        stageKsplit(0, kp); stageVt(0, vp);
        if (nkt > 1) { loadK(kp, 1); loadV(vp, 1); }
        BAR();

        for (int kt = 0; kt < nkt; ++kt) {
            const int cur = kt & 1;
            if (kt + 1 < nkt) {
                stageKsplit(cur ^ 1, kp);
                stageVt(cur ^ 1, vp);
                if (kt + 2 < nkt) { loadK(kp, kt + 2); loadV(vp, kt + 2); }
            }
            // S = QK^T (compensated) -> Pf (wave-private band)
#pragma unroll
            for (int n = 0; n < 4; ++n) {
                const bool fm = (kt == qb) && (n > wave);  // wave-uniform
                f32x4 acc = {0.f, 0.f, 0.f, 0.f};
                if (!fm) {
                    bf16x8 kh0 = *(const bf16x8*)&Khi[cur][(16 * n + lo) * KLD + hi * 8];
                    bf16x8 kh1 = *(const bf16x8*)&Khi[cur][(16 * n + lo) * KLD + 32 + hi * 8];
                    bf16x8 kl0 = *(const bf16x8*)&Klo[cur][(16 * n + lo) * KLD + hi * 8];
                    bf16x8 kl1 = *(const bf16x8*)&Klo[cur][(16 * n + lo) * KLD + 32 + hi * 8];
                    __builtin_amdgcn_s_setprio(1);
                    acc = __builtin_amdgcn_mfma_f32_16x16x32_bf16(qa0h, kh0, acc, 0, 0, 0);
                    acc = __builtin_amdgcn_mfma_f32_16x16x32_bf16(qa1h, kh1, acc, 0, 0, 0);
                    acc = __builtin_amdgcn_mfma_f32_16x16x32_bf16(qa0h, kl0, acc, 0, 0, 0);
                    acc = __builtin_amdgcn_mfma_f32_16x16x32_bf16(qa1h, kl1, acc, 0, 0, 0);
                    acc = __builtin_amdgcn_mfma_f32_16x16x32_bf16(qa0l, kh0, acc, 0, 0, 0);
                    acc = __builtin_amdgcn_mfma_f32_16x16x32_bf16(qa1l, kh1, acc, 0, 0, 0);
                    __builtin_amdgcn_s_setprio(0);
                }
                const int col = 16 * n + lo;
#pragma unroll
                for (int jx = 0; jx < 4; ++jx) {
                    const int row = wave * 16 + hi * 4 + jx;
                    const float p = (!fm && (kt < qb || col <= row)) ? __expf(acc[jx]) * il[jx] : 0.f;
                    Pf[row * PFLD + col] = p;
                }
            }
            // stream own P band to global
            {
                const int r = wave * 16 + (lane >> 2);
                const int c4 = (lane & 3) * 4;
                float* dst = &Pg[((size_t)(b * SEQ) + q0 + r) * SEQ + kt * KT + c4];
                const float* src = &Pf[r * PFLD + c4];
#pragma unroll
                for (int iw = 0; iw < 4; ++iw)
                    *(f32x4*)&dst[16 * iw] = *(const f32x4*)&src[16 * iw];
            }
            // PV: A-frag from own Pf band, B-frag from Vt[cur]
            {
                const float* pr = &Pf[(wave * 16 + lo) * PFLD + hi * 8];
                bf16x8 pa0, pa1;
                {
                    f32x4 a = *(const f32x4*)pr, c2 = *(const f32x4*)(pr + 4);
                    f32x4 d = *(const f32x4*)(pr + 32), e2 = *(const f32x4*)(pr + 36);
#pragma unroll
                    for (int e = 0; e < 4; ++e) {
                        pa0[e] = f2bf(a[e]); pa0[4 + e] = f2bf(c2[e]);
                        pa1[e] = f2bf(d[e]); pa1[4 + e] = f2bf(e2[e]);
                    }
                }
                __builtin_amdgcn_s_setprio(1);
#pragma unroll
                for (int n = 0; n < 4; ++n) {
                    bf16x8 vb0 = *(const bf16x8*)&Vt[cur][(16 * n + lo) * VLD + hi * 8];
                    bf16x8 vb1 = *(const bf16x8*)&Vt[cur][(16 * n + lo) * VLD + 32 + hi * 8];
                    o[n] = __builtin_amdgcn_mfma_f32_16x16x32_bf16(pa0, vb0, o[n], 0, 0, 0);
                    o[n] = __builtin_amdgcn_mfma_f32_16x16x32_bf16(pa1, vb1, o[n], 0, 0, 0);
                }
                __builtin_amdgcn_s_setprio(0);
            }
            BAR();
        }
    }

    // ---- zero-fill fully-masked column tiles (exact 0 == ref underflow) ----
    {
        const int r = tid >> 2;
        float* rowp = &Pg[((size_t)(b * SEQ) + q0 + r) * SEQ];
        const f32x4 z = {0.f, 0.f, 0.f, 0.f};
        for (int cb = nkt * KT + (tid & 3) * 16; cb < SEQ; cb += KT)
#pragma unroll
            for (int iw = 0; iw < 4; ++iw)
                *(f32x4*)&rowp[cb + 4 * iw] = z;
    }
    // ---- O (already normalized: PV used exp*il), fp32 ----
    {
        float* og = &Og[((size_t)(b * SEQ) + q0 + wave * 16 + hi * 4) * DIM + lo];
#pragma unroll
        for (int jx = 0; jx < 4; ++jx)
#pragma unroll
            for (int n = 0; n < 4; ++n)
                og[jx * DIM + n * 16] = o[n][jx];
    }
}

extern "C" void kernel_launch(void* const* d_in, const int* in_sizes, int n_in,
                              void* d_out, int out_size, void* d_ws, size_t ws_size,
                              hipStream_t stream) {
    const float* q = (const float*)d_in[0];
    const float* k = (const float*)d_in[1];
    const float* v = (const float*)d_in[2];
    float* out  = (float*)d_out;                        // [B,T,D] fp32
    float* smqk = out + (size_t)BATCHES * SEQ * DIM;    // [B,T,T] fp32

    sdpa_fused<<<NQB * BATCHES, 256, 0, stream>>>(q, k, v, out, smqk);
}

// Round 13
// 104.630 us; speedup vs baseline: 1.0860x; 1.0081x over previous
//
#include <hip/hip_runtime.h>
#include <hip/hip_bf16.h>

// SDPA, causal, b=16 t=2048 d=64. Outputs FP32: d_out = [ out | sm_qk ].
// R13: latency-chain attack.
//  - T15 pipeline: PV(kt-1) overlaps QK^T(kt). Pb[2] bf16 P-relay (wave-
//    private, no cross-wave sync), Vt[3] ring for V lifetime.
//  - QK^T compensation: Q-side residual only (registers): qh*kh + ql*kh.
//    K residual dropped (Klo LDS gone). S err ~1e-3 std, P err << thr.
//  - P stored to global DIRECTLY from acc regs (no Pf LDS round-trip).
//  - Phase 1 (lean rowsum) as R12: Khi dbuf, 2 MFMA, nmax diagonal trick.
// XCD batch clustering + causal pairing as R5. BAR = lgkm-only barrier.

#define BATCHES 16
#define SEQ 2048
#define DIM 64
#define QB 64
#define KT 64
#define NQB (SEQ / QB) /* 32 */
#define KLD 72   /* K LDS row stride, shorts */
#define VLD 72   /* V^T LDS row stride, shorts */
#define PBLD 72  /* bf16 P-tile stride, shorts */

#define BAR() do { asm volatile("s_waitcnt lgkmcnt(0)" ::: "memory"); \
                   __builtin_amdgcn_s_barrier(); } while (0)

typedef __attribute__((ext_vector_type(8))) short bf16x8;
typedef __attribute__((ext_vector_type(4))) short short4v;
typedef __attribute__((ext_vector_type(4))) float f32x4;

static __device__ __forceinline__ short f2bf(float f) {
    return __builtin_bit_cast(short, __float2bfloat16(f));
}
static __device__ __forceinline__ float bf2f(short s) {
    unsigned int u = ((unsigned int)(unsigned short)s) << 16;
    return __builtin_bit_cast(float, u);
}
static __device__ __forceinline__ void split8(f32x4 a, f32x4 b, float sc,
                                              bf16x8& h, bf16x8& l) {
#pragma unroll
    for (int e = 0; e < 4; ++e) {
        float x = a[e] * sc;
        short hb = f2bf(x);
        h[e] = hb; l[e] = f2bf(x - bf2f(hb));
    }
#pragma unroll
    for (int e = 0; e < 4; ++e) {
        float x = b[e] * sc;
        short hb = f2bf(x);
        h[4 + e] = hb; l[4 + e] = f2bf(x - bf2f(hb));
    }
}

__global__ __launch_bounds__(256, 2) void sdpa_fused(
    const float* __restrict__ Qg, const float* __restrict__ Kg,
    const float* __restrict__ Vg, float* __restrict__ Og, float* __restrict__ Pg)
{
    const int i = blockIdx.x;
    const int g = i & 7;
    const int j = i >> 3;             // 0..63
    const int b = 2 * g + (j >> 5);
    const int jj = j & 31;
    const int qb = (j < 32) ? jj : (31 - jj);
    const int q0 = qb * QB;

    const int tid = threadIdx.x;
    const int lane = tid & 63;
    const int wave = tid >> 6;
    const int lo = lane & 15;
    const int hi = lane >> 4;
    const int sr = tid >> 4;          // K stage rows: sr+16*ii
    const int sc = (tid & 15) * 4;    // stage col
    const int vr = (tid >> 4) * 4;    // V stage rows: vr..vr+3

    __shared__ short Khi[2][KT * KLD];   // 18.4 KB
    __shared__ short Vt [3][DIM * VLD];  // 27.6 KB
    __shared__ short Pb [2][QB * PBLD];  // 18.4 KB  (wave-private bands)

    const float* qB = Qg + (size_t)b * SEQ * DIM;
    const float* kB = Kg + (size_t)b * SEQ * DIM;
    const float* vB = Vg + (size_t)b * SEQ * DIM;

    bf16x8 qa0h, qa0l, qa1h, qa1l;    // Q hi + residual (registers only)
    {
        const float* qr = &qB[(size_t)(q0 + wave * 16 + lo) * DIM + hi * 8];
        split8(*(const f32x4*)qr,        *(const f32x4*)(qr + 4),  0.125f, qa0h, qa0l);
        split8(*(const f32x4*)(qr + 32), *(const f32x4*)(qr + 36), 0.125f, qa1h, qa1l);
    }

    const int nkt = qb + 1;
    float rl[4] = {0.f, 0.f, 0.f, 0.f};

    auto loadK = [&](f32x4* kp, int kt) {
#pragma unroll
        for (int ii = 0; ii < 4; ++ii)
            kp[ii] = *(const f32x4*)&kB[(size_t)(kt * KT + sr + 16 * ii) * DIM + sc];
    };
    auto loadV = [&](f32x4* vp, int kt) {
#pragma unroll
        for (int ii = 0; ii < 4; ++ii)
            vp[ii] = *(const f32x4*)&vB[(size_t)(kt * KT + vr + ii) * DIM + sc];
    };
    auto stageKhi = [&](int buf, const f32x4* kp) {
#pragma unroll
        for (int ii = 0; ii < 4; ++ii) {
            short4v hh;
#pragma unroll
            for (int e = 0; e < 4; ++e) hh[e] = f2bf(kp[ii][e]);
            *(short4v*)&Khi[buf][(sr + 16 * ii) * KLD + sc] = hh;
        }
    };
    auto stageVt = [&](int buf, const f32x4* vp) {
#pragma unroll
        for (int e = 0; e < 4; ++e) {
            short4v tv;
#pragma unroll
            for (int ii = 0; ii < 4; ++ii) tv[ii] = f2bf(vp[ii][e]);
            *(short4v*)&Vt[buf][(sc + e) * VLD + vr] = tv;
        }
    };

    // ================ phase 1: l = sum exp(S), lean ================
    {
        f32x4 kp[4];
        loadK(kp, 0);
        stageKhi(0, kp);
        if (nkt > 1) loadK(kp, 1);
        BAR();
        for (int kt = 0; kt < nkt; ++kt) {
            const int cur = kt & 1;
            if (kt + 1 < nkt) {
                stageKhi(cur ^ 1, kp);
                if (kt + 2 < nkt) loadK(kp, kt + 2);
            }
            const int nmax = (kt == qb) ? (wave + 1) : 4;
            for (int n = 0; n < nmax; ++n) {
                bf16x8 kh0 = *(const bf16x8*)&Khi[cur][(16 * n + lo) * KLD + hi * 8];
                bf16x8 kh1 = *(const bf16x8*)&Khi[cur][(16 * n + lo) * KLD + 32 + hi * 8];
                f32x4 acc = {0.f, 0.f, 0.f, 0.f};
                __builtin_amdgcn_s_setprio(1);
                acc = __builtin_amdgcn_mfma_f32_16x16x32_bf16(qa0h, kh0, acc, 0, 0, 0);
                acc = __builtin_amdgcn_mfma_f32_16x16x32_bf16(qa1h, kh1, acc, 0, 0, 0);
                __builtin_amdgcn_s_setprio(0);
                if (kt < qb) {
#pragma unroll
                    for (int jx = 0; jx < 4; ++jx) rl[jx] += __expf(acc[jx]);
                } else {
                    const int col = 16 * n + lo;
#pragma unroll
                    for (int jx = 0; jx < 4; ++jx)
                        if (col <= wave * 16 + hi * 4 + jx) rl[jx] += __expf(acc[jx]);
                }
            }
            BAR();
        }
    }
#pragma unroll
    for (int m = 1; m <= 8; m <<= 1)
#pragma unroll
        for (int jx = 0; jx < 4; ++jx) rl[jx] += __shfl_xor(rl[jx], m, 16);
    float il[4];
#pragma unroll
    for (int jx = 0; jx < 4; ++jx) il[jx] = 1.0f / rl[jx];

    // ===== phase 2: P=exp(S)*il direct-store + pipelined O=P*V =====
    f32x4 o[4];
#pragma unroll
    for (int n = 0; n < 4; ++n) { o[n][0] = 0.f; o[n][1] = 0.f; o[n][2] = 0.f; o[n][3] = 0.f; }

    // direct P store coords: lane covers (rows hi*4+jx of own band, col 16n+lo)
    float* prowBase = &Pg[((size_t)(b * SEQ) + q0 + wave * 16 + hi * 4) * SEQ + lo];

    {
        f32x4 kp[4], vp[4];
        loadK(kp, 0); loadV(vp, 0);
        stageKhi(0, kp); stageVt(0, vp);
        if (nkt > 1) { loadK(kp, 1); loadV(vp, 1); }
        BAR();

        int vstg = 1, vprev = 2;            // V(kt) in kt%3; stage (kt+1)%3
        for (int kt = 0; kt < nkt; ++kt) {
            const int cur = kt & 1;         // Khi slot of K(kt)
            const int pcur = kt & 1;        // Pb slot for P(kt)
            if (kt + 1 < nkt) {
                stageKhi(cur ^ 1, kp);
                stageVt(vstg, vp);
                if (kt + 2 < nkt) { loadK(kp, kt + 2); loadV(vp, kt + 2); }
            }
            // ---- PV(kt-1): inputs all ready at iter start (overlaps QKT) ----
            if (kt > 0) {
                bf16x8 pa0 = *(const bf16x8*)&Pb[pcur ^ 1][(wave * 16 + lo) * PBLD + hi * 8];
                bf16x8 pa1 = *(const bf16x8*)&Pb[pcur ^ 1][(wave * 16 + lo) * PBLD + 32 + hi * 8];
                __builtin_amdgcn_s_setprio(1);
#pragma unroll
                for (int n = 0; n < 4; ++n) {
                    bf16x8 vb0 = *(const bf16x8*)&Vt[vprev][(16 * n + lo) * VLD + hi * 8];
                    bf16x8 vb1 = *(const bf16x8*)&Vt[vprev][(16 * n + lo) * VLD + 32 + hi * 8];
                    o[n] = __builtin_amdgcn_mfma_f32_16x16x32_bf16(pa0, vb0, o[n], 0, 0, 0);
                    o[n] = __builtin_amdgcn_mfma_f32_16x16x32_bf16(pa1, vb1, o[n], 0, 0, 0);
                }
                __builtin_amdgcn_s_setprio(0);
            }
            // ---- QKT(kt) (Q-side compensated): P = exp(S)*il ----
#pragma unroll
            for (int n = 0; n < 4; ++n) {
                const bool fm = (kt == qb) && (n > wave);  // wave-uniform
                f32x4 acc = {0.f, 0.f, 0.f, 0.f};
                if (!fm) {
                    bf16x8 kh0 = *(const bf16x8*)&Khi[cur][(16 * n + lo) * KLD + hi * 8];
                    bf16x8 kh1 = *(const bf16x8*)&Khi[cur][(16 * n + lo) * KLD + 32 + hi * 8];
                    __builtin_amdgcn_s_setprio(1);
                    acc = __builtin_amdgcn_mfma_f32_16x16x32_bf16(qa0h, kh0, acc, 0, 0, 0);
                    acc = __builtin_amdgcn_mfma_f32_16x16x32_bf16(qa1h, kh1, acc, 0, 0, 0);
                    acc = __builtin_amdgcn_mfma_f32_16x16x32_bf16(qa0l, kh0, acc, 0, 0, 0);
                    acc = __builtin_amdgcn_mfma_f32_16x16x32_bf16(qa1l, kh1, acc, 0, 0, 0);
                    __builtin_amdgcn_s_setprio(0);
                }
                const int col = 16 * n + lo;
                float* pcol = prowBase + kt * KT + 16 * n;
#pragma unroll
                for (int jx = 0; jx < 4; ++jx) {
                    const int row = wave * 16 + hi * 4 + jx;
                    const float p = (!fm && (kt < qb || col <= row)) ? __expf(acc[jx]) * il[jx] : 0.f;
                    pcol[(size_t)jx * SEQ] = p;                          // direct store
                    Pb[pcur][row * PBLD + col] = f2bf(p);                // PV relay
                }
            }
            BAR();
            vprev = (vprev == 2) ? 0 : vprev + 1;
            vstg  = (vstg  == 2) ? 0 : vstg  + 1;
        }
        // ---- epilogue: PV(nkt-1) (same-wave Pb/Vt data, lgkm-ordered) ----
        {
            const int pl = (nkt - 1) & 1;
            const int vl = (nkt - 1) % 3;
            bf16x8 pa0 = *(const bf16x8*)&Pb[pl][(wave * 16 + lo) * PBLD + hi * 8];
            bf16x8 pa1 = *(const bf16x8*)&Pb[pl][(wave * 16 + lo) * PBLD + 32 + hi * 8];
#pragma unroll
            for (int n = 0; n < 4; ++n) {
                bf16x8 vb0 = *(const bf16x8*)&Vt[vl][(16 * n + lo) * VLD + hi * 8];
                bf16x8 vb1 = *(const bf16x8*)&Vt[vl][(16 * n + lo) * VLD + 32 + hi * 8];
                o[n] = __builtin_amdgcn_mfma_f32_16x16x32_bf16(pa0, vb0, o[n], 0, 0, 0);
                o[n] = __builtin_amdgcn_mfma_f32_16x16x32_bf16(pa1, vb1, o[n], 0, 0, 0);
            }
        }
    }

    // ---- zero-fill fully-masked column tiles (exact 0 == ref underflow) ----
    {
        const int r = tid >> 2;
        float* rowp = &Pg[((size_t)(b * SEQ) + q0 + r) * SEQ];
        const f32x4 z = {0.f, 0.f, 0.f, 0.f};
        for (int cb = nkt * KT + (tid & 3) * 16; cb < SEQ; cb += KT)
#pragma unroll
            for (int iw = 0; iw < 4; ++iw)
                *(f32x4*)&rowp[cb + 4 * iw] = z;
    }
    // ---- O (already normalized: PV used exp*il), fp32 ----
    {
        float* og = &Og[((size_t)(b * SEQ) + q0 + wave * 16 + hi * 4) * DIM + lo];
#pragma unroll
        for (int jx = 0; jx < 4; ++jx)
#pragma unroll
            for (int n = 0; n < 4; ++n)
                og[jx * DIM + n * 16] = o[n][jx];
    }
}

extern "C" void kernel_launch(void* const* d_in, const int* in_sizes, int n_in,
                              void* d_out, int out_size, void* d_ws, size_t ws_size,
                              hipStream_t stream) {
    const float* q = (const float*)d_in[0];
    const float* k = (const float*)d_in[1];
    const float* v = (const float*)d_in[2];
    float* out  = (float*)d_out;                        // [B,T,D] fp32
    float* smqk = out + (size_t)BATCHES * SEQ * DIM;    // [B,T,T] fp32

    sdpa_fused<<<NQB * BATCHES, 256, 0, stream>>>(q, k, v, out, smqk);
}